// Round 14
// baseline (702.265 us; speedup 1.0000x reference)
//
#include <hip/hip_runtime.h>
#include <hip/hip_bf16.h>

#define DIM 256
#define HEADS 4
#define NEG_SLOPE 0.01f

typedef unsigned short u16;
typedef __attribute__((ext_vector_type(8))) short short8;
typedef __attribute__((ext_vector_type(4))) float f32x4;

// ---- bf16 helpers ----
__device__ __forceinline__ u16 f2bf(float f) {           // RTN-even
    unsigned u = __float_as_uint(f);
    unsigned r = (u + 0x7fffu + ((u >> 16) & 1u)) >> 16;
    return (u16)r;
}
__device__ __forceinline__ unsigned cvt2(float a, float b) {   // native v_cvt_pk path
    __hip_bfloat162 h = __float22bfloat162_rn(make_float2(a, b));
    unsigned u;
    __builtin_memcpy(&u, &h, 4);
    return u;
}

// K0a: transpose w_q (k-major fp32) -> BThi (n-major bf16, RTN)
__global__ __launch_bounds__(256) void prepb_kernel(const float* __restrict__ B,
                                                    u16* __restrict__ BThi) {
    int k = blockIdx.x;
    int n = threadIdx.x;
    BThi[n * 256 + k] = f2bf(B[k * 256 + n]);
}

// K0b: wg[k][h] = sum_{d<64} w_q[k][h*64+d] * weight[h][64+d]   (256x4 fp32)
__global__ __launch_bounds__(256) void prepwg_kernel(const float* __restrict__ wq,
                                                     const float* __restrict__ weight,
                                                     float* __restrict__ wg) {
    int k = threadIdx.x;
#pragma unroll
    for (int h = 0; h < 4; ++h) {
        float s = 0.f;
        for (int d = 0; d < 64; ++d)
            s = fmaf(wq[k * 256 + h * 64 + d], weight[h * 128 + 64 + d], s);
        wg[k * 4 + h] = s;
    }
}

// K1: beta[j,h] = sum_{d<64} x_edge[j, h*64+d] * weight[h, d]
__global__ __launch_bounds__(256) void beta_kernel(const float* __restrict__ xe,
                                                   const float* __restrict__ weight,
                                                   float* __restrict__ beta, int NE) {
    int wid = blockIdx.x * 4 + (threadIdx.x >> 6);
    if (wid >= NE) return;
    int lane = threadIdx.x & 63;
    int h = lane >> 4;
    float4 v = *reinterpret_cast<const float4*>(xe + (size_t)wid * DIM + lane * 4);
    float4 w = *reinterpret_cast<const float4*>(weight + h * 128 + (lane & 15) * 4);
    float p = v.x * w.x + v.y * w.y + v.z * w.z + v.w * w.w;
    p += __shfl_xor(p, 1);
    p += __shfl_xor(p, 2);
    p += __shfl_xor(p, 4);
    p += __shfl_xor(p, 8);
    if ((lane & 15) == 0) beta[(size_t)wid * 4 + h] = p;
}

// K2: one wave per qualifier row. gamma[e,h] = x_q[e,:] . wg[:,h] (fp32 exact),
// logit = leaky(beta[eid]+gamma), ex = exp, segsum atomicAdd, counts histogram.
__global__ __launch_bounds__(256) void gamma_kernel(const float* __restrict__ xq,
                                                    const float* __restrict__ wg,
                                                    const float* __restrict__ beta,
                                                    const int* __restrict__ eids,
                                                    float* __restrict__ exv,
                                                    float* __restrict__ segsum,
                                                    unsigned* __restrict__ counts, int NQ) {
    int e = blockIdx.x * 4 + (threadIdx.x >> 6);
    if (e >= NQ) return;
    int lane = threadIdx.x & 63;
    float4 x = *reinterpret_cast<const float4*>(xq + (size_t)e * DIM + lane * 4);
    float4 p = make_float4(0.f, 0.f, 0.f, 0.f);
    const float xs[4] = {x.x, x.y, x.z, x.w};
#pragma unroll
    for (int i = 0; i < 4; ++i) {
        float4 w = *reinterpret_cast<const float4*>(wg + (lane * 4 + i) * 4);
        p.x = fmaf(xs[i], w.x, p.x);
        p.y = fmaf(xs[i], w.y, p.y);
        p.z = fmaf(xs[i], w.z, p.z);
        p.w = fmaf(xs[i], w.w, p.w);
    }
#pragma unroll
    for (int d = 1; d < 64; d <<= 1) {
        p.x += __shfl_xor(p.x, d);
        p.y += __shfl_xor(p.y, d);
        p.z += __shfl_xor(p.z, d);
        p.w += __shfl_xor(p.w, d);
    }
    if (lane == 0) {
        int j = eids[e];
        float4 b = *reinterpret_cast<const float4*>(beta + (size_t)j * 4);
        float l[4] = {b.x + p.x, b.y + p.y, b.z + p.z, b.w + p.w};
        float ex[4];
#pragma unroll
        for (int h = 0; h < 4; ++h) {
            l[h] = l[h] > 0.f ? l[h] : NEG_SLOPE * l[h];
            ex[h] = __expf(l[h]);
        }
        *reinterpret_cast<float4*>(exv + (size_t)e * 4) = make_float4(ex[0], ex[1], ex[2], ex[3]);
#pragma unroll
        for (int h = 0; h < 4; ++h) atomicAdd(&segsum[(size_t)j * 4 + h], ex[h]);
        atomicAdd(&counts[j], 1u);
    }
}

// ---- CSR build ----
__global__ __launch_bounds__(256) void scan1_kernel(const unsigned* __restrict__ counts,
                                                    unsigned* __restrict__ offs,
                                                    unsigned* __restrict__ blocksums, int NE) {
    __shared__ unsigned s[256];
    int t = threadIdx.x;
    int base = blockIdx.x * 1024 + t * 4;
    unsigned v[4], sum = 0;
#pragma unroll
    for (int i = 0; i < 4; ++i) {
        v[i] = (base + i < NE) ? counts[base + i] : 0u;
        sum += v[i];
    }
    s[t] = sum;
    __syncthreads();
    for (int off = 1; off < 256; off <<= 1) {
        unsigned y = (t >= off) ? s[t - off] : 0u;
        __syncthreads();
        s[t] += y;
        __syncthreads();
    }
    unsigned excl = s[t] - sum;
#pragma unroll
    for (int i = 0; i < 4; ++i) {
        if (base + i < NE) offs[base + i] = excl;
        excl += v[i];
    }
    if (t == 255) blocksums[blockIdx.x] = s[255];
}

__global__ __launch_bounds__(256) void scan2_kernel(unsigned* __restrict__ blocksums, int NB) {
    __shared__ unsigned s[256];
    int t = threadIdx.x;
    unsigned v = (t < NB) ? blocksums[t] : 0u;
    s[t] = v;
    __syncthreads();
    for (int off = 1; off < 256; off <<= 1) {
        unsigned y = (t >= off) ? s[t - off] : 0u;
        __syncthreads();
        s[t] += y;
        __syncthreads();
    }
    if (t < NB) blocksums[t] = s[t] - v;
}

__global__ __launch_bounds__(256) void scan3_kernel(unsigned* __restrict__ offs,
                                                    const unsigned* __restrict__ blocksums,
                                                    unsigned* __restrict__ cursor, int NE) {
    int t = threadIdx.x;
    int base = blockIdx.x * 1024 + t * 4;
    unsigned add = blocksums[blockIdx.x];
#pragma unroll
    for (int i = 0; i < 4; ++i) {
        if (base + i < NE) {
            unsigned o = offs[base + i] + add;
            offs[base + i] = o;
            cursor[base + i] = o;
        }
    }
}

__global__ __launch_bounds__(256) void fill_kernel(const int* __restrict__ eids,
                                                   unsigned* __restrict__ cursor,
                                                   int* __restrict__ qlist, int NQ) {
    int e = blockIdx.x * blockDim.x + threadIdx.x;
    if (e >= NQ) return;
    int j = eids[e];
    unsigned pos = atomicAdd(&cursor[j], 1u);
    qlist[pos] = e;
}

// K5: fused aggregate + GEMM. Block = 16 edges, 256 threads.
// Phase A: 16 threads/edge (16 cols each), gather x_q rows once, weighted-sum
//   into acc[4 heads][16 cols] (fp32), write bf16 LDS tile agg[16e*4h][256k]
//   (chunk-swizzled). ONE barrier.
// Phase B: wave w = head w. A-frags from LDS, B-frags direct from BThi (L2),
//   32 MFMAs -> C 16x64, write out[j, w*64..].
__global__ __launch_bounds__(256, 3) void aggmm_kernel(const float* __restrict__ xq,
                                                       const u16* __restrict__ BThi,
                                                       const float* __restrict__ exv,
                                                       const float* __restrict__ segsum,
                                                       const unsigned* __restrict__ offs,
                                                       const unsigned* __restrict__ counts,
                                                       const int* __restrict__ qlist,
                                                       float* __restrict__ out, int NE) {
    __shared__ u16 agg_s[64 * 256];   // [row = e_loc*4 + h][k], 16B-chunk swizzled

    const int t = threadIdx.x;
    const int e_loc = t >> 4;        // 0..15
    const int tc = t & 15;           // 16-col group
    const long j = (long)blockIdx.x * 16 + e_loc;
    const bool ok_e = j < NE;

    f32x4 acc[4][4];                 // [head][4 cols each x4 = 16 cols]
#pragma unroll
    for (int h = 0; h < 4; ++h)
#pragma unroll
        for (int i = 0; i < 4; ++i) acc[h][i] = (f32x4){0.f, 0.f, 0.f, 0.f};

    if (ok_e) {
        unsigned beg = offs[j];
        unsigned n = counts[j];
        float4 ss = *reinterpret_cast<const float4*>(segsum + (size_t)j * 4);
        float inv[4] = {1.f / (ss.x + 1e-16f), 1.f / (ss.y + 1e-16f),
                        1.f / (ss.z + 1e-16f), 1.f / (ss.w + 1e-16f)};
        for (unsigned i = 0; i < n; ++i) {
            int q = qlist[beg + i];
            float4 e4 = *reinterpret_cast<const float4*>(exv + (size_t)q * 4);
            float w[4] = {e4.x * inv[0], e4.y * inv[1], e4.z * inv[2], e4.w * inv[3]};
            const float* xr = xq + (size_t)q * DIM + tc * 16;
            float4 xv[4];
#pragma unroll
            for (int c = 0; c < 4; ++c) xv[c] = *reinterpret_cast<const float4*>(xr + c * 4);
#pragma unroll
            for (int h = 0; h < 4; ++h)
#pragma unroll
                for (int c = 0; c < 4; ++c) {
                    acc[h][c].x = fmaf(w[h], xv[c].x, acc[h][c].x);
                    acc[h][c].y = fmaf(w[h], xv[c].y, acc[h][c].y);
                    acc[h][c].z = fmaf(w[h], xv[c].z, acc[h][c].z);
                    acc[h][c].w = fmaf(w[h], xv[c].w, acc[h][c].w);
                }
        }
    }

    // write agg tile (rows fully covered; j>=NE rows are zeros)
#pragma unroll
    for (int h = 0; h < 4; ++h) {
        int row = e_loc * 4 + h;
#pragma unroll
        for (int c = 0; c < 2; ++c) {    // two 16B chunks (8 bf16 each)
            uint4 wv;
            wv.x = cvt2(acc[h][c * 2].x, acc[h][c * 2].y);
            wv.y = cvt2(acc[h][c * 2].z, acc[h][c * 2].w);
            wv.z = cvt2(acc[h][c * 2 + 1].x, acc[h][c * 2 + 1].y);
            wv.w = cvt2(acc[h][c * 2 + 1].z, acc[h][c * 2 + 1].w);
            int chunk = (tc * 2 + c) ^ (row & 7);
            *reinterpret_cast<uint4*>(&agg_s[row * 256 + chunk * 8]) = wv;
        }
    }
    __syncthreads();

    // Phase B: MFMA. wave = head.
    const int wave = t >> 6;
    const int lane = t & 63;
    const int lr = lane & 15;
    const int kg = lane >> 4;
    const int arow = lr * 4 + wave;               // LDS row for this lane's A-frag
    const u16* brows[4];
#pragma unroll
    for (int n = 0; n < 4; ++n)
        brows[n] = BThi + (wave * 64 + n * 16 + lr) * 256 + kg * 8;

    f32x4 cc[4];
#pragma unroll
    for (int n = 0; n < 4; ++n) cc[n] = (f32x4){0.f, 0.f, 0.f, 0.f};

#pragma unroll
    for (int k0 = 0; k0 < DIM; k0 += 32) {
        int chunk = ((k0 >> 3) + kg) ^ (arow & 7);
        short8 ah = *reinterpret_cast<const short8*>(&agg_s[arow * 256 + chunk * 8]);
#pragma unroll
        for (int n = 0; n < 4; ++n) {
            short8 bh = *reinterpret_cast<const short8*>(brows[n] + k0);
            cc[n] = __builtin_amdgcn_mfma_f32_16x16x32_bf16(ah, bh, cc[n], 0, 0, 0);
        }
    }

    // epilogue: C row = kg*4 + r (edge), col = wave*64 + n*16 + lr
#pragma unroll
    for (int r = 0; r < 4; ++r) {
        long jj = (long)blockIdx.x * 16 + kg * 4 + r;
        if (jj < NE) {
            float* orow = out + jj * DIM + wave * 64 + lr;
#pragma unroll
            for (int n = 0; n < 4; ++n) orow[n * 16] = cc[n][r];
        }
    }
}

extern "C" void kernel_launch(void* const* d_in, const int* in_sizes, int n_in,
                              void* d_out, int out_size, void* d_ws, size_t ws_size,
                              hipStream_t stream) {
    (void)n_in; (void)out_size; (void)ws_size;
    const float* x_q    = (const float*)d_in[0];
    const float* x_edge = (const float*)d_in[1];
    const float* w_q    = (const float*)d_in[2];
    const float* weight = (const float*)d_in[3];
    const int*   eids   = (const int*)d_in[4];
    const int NQ = in_sizes[0] / DIM;   // 500000
    const int NE = in_sizes[1] / DIM;   // 250000
    float* out = (float*)d_out;

    // workspace layout (no xq buffer anymore)
    float*    exv       = (float*)d_ws;                         // NQ*4
    float*    beta      = exv + (size_t)NQ * 4;                 // NE*4
    float*    segsum    = beta + (size_t)NE * 4;                // NE*4
    unsigned* counts    = (unsigned*)(segsum + (size_t)NE * 4); // NE
    unsigned* offs      = counts + NE;                          // NE
    unsigned* cursor    = offs + NE;                            // NE
    int*      qlist     = (int*)(cursor + NE);                  // NQ
    unsigned* blocksums = (unsigned*)(qlist + NQ);              // 256
    u16*      BThi      = (u16*)(blocksums + 256);              // 256*256
    float*    wg        = (float*)(BThi + 256 * 256);           // 256*4

    const int NB = (NE + 1023) / 1024;

    hipMemsetAsync(segsum, 0, (size_t)NE * 4 * sizeof(float), stream);
    hipMemsetAsync(counts, 0, (size_t)NE * sizeof(unsigned), stream);

    prepb_kernel<<<256, 256, 0, stream>>>(w_q, BThi);
    prepwg_kernel<<<1, 256, 0, stream>>>(w_q, weight, wg);
    beta_kernel<<<(NE + 3) / 4, 256, 0, stream>>>(x_edge, weight, beta, NE);
    gamma_kernel<<<(NQ + 3) / 4, 256, 0, stream>>>(x_q, wg, beta, eids, exv, segsum, counts, NQ);
    scan1_kernel<<<NB, 256, 0, stream>>>(counts, offs, blocksums, NE);
    scan2_kernel<<<1, 256, 0, stream>>>(blocksums, NB);
    scan3_kernel<<<NB, 256, 0, stream>>>(offs, blocksums, cursor, NE);
    fill_kernel<<<(NQ + 255) / 256, 256, 0, stream>>>(eids, cursor, qlist, NQ);
    aggmm_kernel<<<(NE + 15) / 16, 256, 0, stream>>>(x_q, BThi, exv, segsum, offs, counts,
                                                     qlist, out, NE);
}

// Round 16
// 681.809 us; speedup vs baseline: 1.0300x; 1.0300x over previous
//
#include <hip/hip_runtime.h>
#include <hip/hip_bf16.h>

#define DIM 256
#define HEADS 4
#define NEG_SLOPE 0.01f

typedef unsigned short u16;
typedef __attribute__((ext_vector_type(8))) short short8;
typedef __attribute__((ext_vector_type(4))) float f32x4;

// ---- bf16 helpers ----
__device__ __forceinline__ u16 f2bf(float f) {           // RTN-even
    unsigned u = __float_as_uint(f);
    unsigned r = (u + 0x7fffu + ((u >> 16) & 1u)) >> 16;
    return (u16)r;
}
__device__ __forceinline__ unsigned cvt2(float a, float b) {   // native v_cvt_pk path
    __hip_bfloat162 h = __float22bfloat162_rn(make_float2(a, b));
    unsigned u;
    __builtin_memcpy(&u, &h, 4);
    return u;
}

// K0a: transpose w_q (k-major fp32) -> BThi (n-major bf16, RTN)
__global__ __launch_bounds__(256) void prepb_kernel(const float* __restrict__ B,
                                                    u16* __restrict__ BThi) {
    int k = blockIdx.x;
    int n = threadIdx.x;
    BThi[n * 256 + k] = f2bf(B[k * 256 + n]);
}

// K0b: wg[k][h] = sum_{d<64} w_q[k][h*64+d] * weight[h][64+d]   (256x4 fp32)
__global__ __launch_bounds__(256) void prepwg_kernel(const float* __restrict__ wq,
                                                     const float* __restrict__ weight,
                                                     float* __restrict__ wg) {
    int k = threadIdx.x;
#pragma unroll
    for (int h = 0; h < 4; ++h) {
        float s = 0.f;
        for (int d = 0; d < 64; ++d)
            s = fmaf(wq[k * 256 + h * 64 + d], weight[h * 128 + 64 + d], s);
        wg[k * 4 + h] = s;
    }
}

// K1: beta[j,h] = sum_{d<64} x_edge[j, h*64+d] * weight[h, d]
__global__ __launch_bounds__(256) void beta_kernel(const float* __restrict__ xe,
                                                   const float* __restrict__ weight,
                                                   float* __restrict__ beta, int NE) {
    int wid = blockIdx.x * 4 + (threadIdx.x >> 6);
    if (wid >= NE) return;
    int lane = threadIdx.x & 63;
    int h = lane >> 4;
    float4 v = *reinterpret_cast<const float4*>(xe + (size_t)wid * DIM + lane * 4);
    float4 w = *reinterpret_cast<const float4*>(weight + h * 128 + (lane & 15) * 4);
    float p = v.x * w.x + v.y * w.y + v.z * w.z + v.w * w.w;
    p += __shfl_xor(p, 1);
    p += __shfl_xor(p, 2);
    p += __shfl_xor(p, 4);
    p += __shfl_xor(p, 8);
    if ((lane & 15) == 0) beta[(size_t)wid * 4 + h] = p;
}

// K2: one wave per qualifier row. gamma[e,h] = x_q[e,:] . wg[:,h] (fp32 exact),
// logit = leaky(beta[eid]+gamma), ex = exp, segsum atomicAdd, counts histogram.
__global__ __launch_bounds__(256) void gamma_kernel(const float* __restrict__ xq,
                                                    const float* __restrict__ wg,
                                                    const float* __restrict__ beta,
                                                    const int* __restrict__ eids,
                                                    float* __restrict__ exv,
                                                    float* __restrict__ segsum,
                                                    unsigned* __restrict__ counts, int NQ) {
    int e = blockIdx.x * 4 + (threadIdx.x >> 6);
    if (e >= NQ) return;
    int lane = threadIdx.x & 63;
    float4 x = *reinterpret_cast<const float4*>(xq + (size_t)e * DIM + lane * 4);
    float4 p = make_float4(0.f, 0.f, 0.f, 0.f);
    const float xs[4] = {x.x, x.y, x.z, x.w};
#pragma unroll
    for (int i = 0; i < 4; ++i) {
        float4 w = *reinterpret_cast<const float4*>(wg + (lane * 4 + i) * 4);
        p.x = fmaf(xs[i], w.x, p.x);
        p.y = fmaf(xs[i], w.y, p.y);
        p.z = fmaf(xs[i], w.z, p.z);
        p.w = fmaf(xs[i], w.w, p.w);
    }
#pragma unroll
    for (int d = 1; d < 64; d <<= 1) {
        p.x += __shfl_xor(p.x, d);
        p.y += __shfl_xor(p.y, d);
        p.z += __shfl_xor(p.z, d);
        p.w += __shfl_xor(p.w, d);
    }
    if (lane == 0) {
        int j = eids[e];
        float4 b = *reinterpret_cast<const float4*>(beta + (size_t)j * 4);
        float l[4] = {b.x + p.x, b.y + p.y, b.z + p.z, b.w + p.w};
        float ex[4];
#pragma unroll
        for (int h = 0; h < 4; ++h) {
            l[h] = l[h] > 0.f ? l[h] : NEG_SLOPE * l[h];
            ex[h] = __expf(l[h]);
        }
        *reinterpret_cast<float4*>(exv + (size_t)e * 4) = make_float4(ex[0], ex[1], ex[2], ex[3]);
#pragma unroll
        for (int h = 0; h < 4; ++h) atomicAdd(&segsum[(size_t)j * 4 + h], ex[h]);
        atomicAdd(&counts[j], 1u);
    }
}

// ---- CSR build ----
__global__ __launch_bounds__(256) void scan1_kernel(const unsigned* __restrict__ counts,
                                                    unsigned* __restrict__ offs,
                                                    unsigned* __restrict__ blocksums, int NE) {
    __shared__ unsigned s[256];
    int t = threadIdx.x;
    int base = blockIdx.x * 1024 + t * 4;
    unsigned v[4], sum = 0;
#pragma unroll
    for (int i = 0; i < 4; ++i) {
        v[i] = (base + i < NE) ? counts[base + i] : 0u;
        sum += v[i];
    }
    s[t] = sum;
    __syncthreads();
    for (int off = 1; off < 256; off <<= 1) {
        unsigned y = (t >= off) ? s[t - off] : 0u;
        __syncthreads();
        s[t] += y;
        __syncthreads();
    }
    unsigned excl = s[t] - sum;
#pragma unroll
    for (int i = 0; i < 4; ++i) {
        if (base + i < NE) offs[base + i] = excl;
        excl += v[i];
    }
    if (t == 255) blocksums[blockIdx.x] = s[255];
}

__global__ __launch_bounds__(256) void scan2_kernel(unsigned* __restrict__ blocksums, int NB) {
    __shared__ unsigned s[256];
    int t = threadIdx.x;
    unsigned v = (t < NB) ? blocksums[t] : 0u;
    s[t] = v;
    __syncthreads();
    for (int off = 1; off < 256; off <<= 1) {
        unsigned y = (t >= off) ? s[t - off] : 0u;
        __syncthreads();
        s[t] += y;
        __syncthreads();
    }
    if (t < NB) blocksums[t] = s[t] - v;
}

__global__ __launch_bounds__(256) void scan3_kernel(unsigned* __restrict__ offs,
                                                    const unsigned* __restrict__ blocksums,
                                                    unsigned* __restrict__ cursor, int NE) {
    int t = threadIdx.x;
    int base = blockIdx.x * 1024 + t * 4;
    unsigned add = blocksums[blockIdx.x];
#pragma unroll
    for (int i = 0; i < 4; ++i) {
        if (base + i < NE) {
            unsigned o = offs[base + i] + add;
            offs[base + i] = o;
            cursor[base + i] = o;
        }
    }
}

__global__ __launch_bounds__(256) void fill_kernel(const int* __restrict__ eids,
                                                   unsigned* __restrict__ cursor,
                                                   int* __restrict__ qlist, int NQ) {
    int e = blockIdx.x * blockDim.x + threadIdx.x;
    if (e >= NQ) return;
    int j = eids[e];
    unsigned pos = atomicAdd(&cursor[j], 1u);
    qlist[pos] = e;
}

// K5: fused aggregate + GEMM. Block = 512 threads = 8 waves = 16 edges.
// Phase A (wave-per-edge, 2 edges/wave): lane covers cols lane*4..+3 of the
//   x_q row (64 lanes = 1KB coalesced read per qualifier); weight = ex*inv
//   (normalized HERE, exactly like r14). Write bf16 LDS tile with r14's
//   proven swizzle: phys_chunk = logical_chunk ^ (row & 7).
// Phase B: wave w -> head h=w>>1, col-pair gp=w&1; A-frags from LDS (r14's
//   exact read), B-frags direct from BThi (L2). No epilogue division.
__global__ __launch_bounds__(512, 4) void aggmm_kernel(const float* __restrict__ xq,
                                                       const u16* __restrict__ BThi,
                                                       const float* __restrict__ exv,
                                                       const float* __restrict__ segsum,
                                                       const unsigned* __restrict__ offs,
                                                       const unsigned* __restrict__ counts,
                                                       const int* __restrict__ qlist,
                                                       float* __restrict__ out, int NE) {
    __shared__ u16 agg_s[64 * 256];   // 32 KB: [row = e_loc*4 + h][k]

    const int t = threadIdx.x;
    const int w = t >> 6;            // wave 0..7
    const int lane = t & 63;

    // ---------- Phase A: wave-per-edge aggregation (normalized weights) ----------
    for (int e2 = 0; e2 < 2; ++e2) {
        const int e_loc = w * 2 + e2;               // 0..15
        const long j = (long)blockIdx.x * 16 + e_loc;
        f32x4 a0 = (f32x4){0.f, 0.f, 0.f, 0.f};
        f32x4 a1 = a0, a2 = a0, a3 = a0;            // per-head accumulators (4 cols each)
        if (j < NE) {
            const unsigned beg = offs[j];
            const unsigned n = counts[j];
            float4 ss = *reinterpret_cast<const float4*>(segsum + (size_t)j * 4);
            const float inv0 = 1.f / (ss.x + 1e-16f);
            const float inv1 = 1.f / (ss.y + 1e-16f);
            const float inv2 = 1.f / (ss.z + 1e-16f);
            const float inv3 = 1.f / (ss.w + 1e-16f);
            const float* xcol = xq + lane * 4;
#pragma unroll 2
            for (unsigned i = 0; i < n; ++i) {
                int q = qlist[beg + i];
                float4 e4 = *reinterpret_cast<const float4*>(exv + (size_t)q * 4);
                float4 xv = *reinterpret_cast<const float4*>(xcol + (size_t)q * DIM);
                f32x4 xvv = {xv.x, xv.y, xv.z, xv.w};
                a0 += (e4.x * inv0) * xvv;
                a1 += (e4.y * inv1) * xvv;
                a2 += (e4.z * inv2) * xvv;
                a3 += (e4.w * inv3) * xvv;
            }
        }
        // write 4 rows; r14 swizzle: phys_chunk = (lane>>1) ^ (row & 7)
        const int halfsel = (lane & 1) * 4;
        f32x4 accs[4] = {a0, a1, a2, a3};
#pragma unroll
        for (int h = 0; h < 4; ++h) {
            int row = e_loc * 4 + h;
            int chunk = (lane >> 1) ^ (row & 7);
            uint2 wv = make_uint2(cvt2(accs[h][0], accs[h][1]), cvt2(accs[h][2], accs[h][3]));
            *reinterpret_cast<uint2*>(&agg_s[row * 256 + chunk * 8 + halfsel]) = wv;
        }
    }
    __syncthreads();

    // ---------- Phase B: MFMA (r14's exact read pattern, 8-wave split) ----------
    const int h = w >> 1;
    const int gp = w & 1;
    const int lr = lane & 15;
    const int kg = lane >> 4;
    const int rowA = lr * 4 + h;                  // edge lr, head h
    const u16* bptr0 = BThi + (h * 64 + gp * 32 + lr) * 256 + kg * 8;
    const u16* bptr1 = bptr0 + 16 * 256;

    f32x4 cc0 = (f32x4){0.f, 0.f, 0.f, 0.f};
    f32x4 cc1 = cc0;
#pragma unroll
    for (int s = 0; s < 8; ++s) {
        int phys = (s * 4 + kg) ^ (rowA & 7);
        short8 ah = *reinterpret_cast<const short8*>(&agg_s[rowA * 256 + phys * 8]);
        short8 b0 = *reinterpret_cast<const short8*>(bptr0 + s * 32);
        short8 b1 = *reinterpret_cast<const short8*>(bptr1 + s * 32);
        cc0 = __builtin_amdgcn_mfma_f32_16x16x32_bf16(ah, b0, cc0, 0, 0, 0);
        cc1 = __builtin_amdgcn_mfma_f32_16x16x32_bf16(ah, b1, cc1, 0, 0, 0);
    }
#pragma unroll
    for (int r = 0; r < 4; ++r) {
        long jj = (long)blockIdx.x * 16 + kg * 4 + r;
        if (jj < NE) {
            float* orow = out + jj * DIM + h * 64 + gp * 32 + lr;
            orow[0]  = cc0[r];
            orow[16] = cc1[r];
        }
    }
}

extern "C" void kernel_launch(void* const* d_in, const int* in_sizes, int n_in,
                              void* d_out, int out_size, void* d_ws, size_t ws_size,
                              hipStream_t stream) {
    (void)n_in; (void)out_size; (void)ws_size;
    const float* x_q    = (const float*)d_in[0];
    const float* x_edge = (const float*)d_in[1];
    const float* w_q    = (const float*)d_in[2];
    const float* weight = (const float*)d_in[3];
    const int*   eids   = (const int*)d_in[4];
    const int NQ = in_sizes[0] / DIM;   // 500000
    const int NE = in_sizes[1] / DIM;   // 250000
    float* out = (float*)d_out;

    // workspace layout
    float*    exv       = (float*)d_ws;                         // NQ*4
    float*    beta      = exv + (size_t)NQ * 4;                 // NE*4
    float*    segsum    = beta + (size_t)NE * 4;                // NE*4
    unsigned* counts    = (unsigned*)(segsum + (size_t)NE * 4); // NE
    unsigned* offs      = counts + NE;                          // NE
    unsigned* cursor    = offs + NE;                            // NE
    int*      qlist     = (int*)(cursor + NE);                  // NQ
    unsigned* blocksums = (unsigned*)(qlist + NQ);              // 256
    u16*      BThi      = (u16*)(blocksums + 256);              // 256*256
    float*    wg        = (float*)(BThi + 256 * 256);           // 256*4

    const int NB = (NE + 1023) / 1024;

    hipMemsetAsync(segsum, 0, (size_t)NE * 4 * sizeof(float), stream);
    hipMemsetAsync(counts, 0, (size_t)NE * sizeof(unsigned), stream);

    prepb_kernel<<<256, 256, 0, stream>>>(w_q, BThi);
    prepwg_kernel<<<1, 256, 0, stream>>>(w_q, weight, wg);
    beta_kernel<<<(NE + 3) / 4, 256, 0, stream>>>(x_edge, weight, beta, NE);
    gamma_kernel<<<(NQ + 3) / 4, 256, 0, stream>>>(x_q, wg, beta, eids, exv, segsum, counts, NQ);
    scan1_kernel<<<NB, 256, 0, stream>>>(counts, offs, blocksums, NE);
    scan2_kernel<<<1, 256, 0, stream>>>(blocksums, NB);
    scan3_kernel<<<NB, 256, 0, stream>>>(offs, blocksums, cursor, NE);
    fill_kernel<<<(NQ + 255) / 256, 256, 0, stream>>>(eids, cursor, qlist, NQ);
    aggmm_kernel<<<(NE + 15) / 16, 512, 0, stream>>>(x_q, BThi, exv, segsum, offs, counts,
                                                     qlist, out, NE);
}